// Round 13
// baseline (310.470 us; speedup 1.0000x reference)
//
#include <hip/hip_runtime.h>
#include <stdint.h>

#define D_MODEL 768
#define BATCH   16
#define SEQ     2048
#define M_ROWS  (BATCH * SEQ)   // 32768
#define LN_EPS  1e-5f

#define CHUNKS  64
#define CLEN    (SEQ / CHUNKS)  // 32
#define PFB     8               // prefetch depth, phase 2

typedef __attribute__((ext_vector_type(4))) float        f32x4;
typedef __attribute__((ext_vector_type(8))) __bf16       bf16x8;
typedef __attribute__((ext_vector_type(2))) unsigned int u32x2;

__device__ __forceinline__ unsigned short f2bf(float f) {
    union { float f; uint32_t u; } v; v.f = f;
    uint32_t u = v.u;
    uint32_t r = (u + 0x7FFFu + ((u >> 16) & 1u)) >> 16;   // RNE
    return (unsigned short)r;
}
__device__ __forceinline__ float bf2f(unsigned short u) {
    union { uint32_t u; float f; } v; v.u = (uint32_t)u << 16; return v.f;
}
// extract element k (0..3) of a packed quad (4 bf16 in 8B)
__device__ __forceinline__ float bfx(u32x2 v, int k) {
    unsigned int w = (k & 2) ? v[1] : v[0];
    return bf2f((unsigned short)(w >> ((k & 1) * 16)));
}

__device__ __forceinline__ void gload_lds16(const void* g, void* l) {
    __builtin_amdgcn_global_load_lds(
        (const __attribute__((address_space(1))) unsigned int*)g,
        (__attribute__((address_space(3))) unsigned int*)l,
        16, 0, 0);
}

// ---------------- Kernel 1: x->bf16 + decay GEMV, and W->bf16 (merged, block-uniform split) ----
__global__ __launch_bounds__(256) void k_conv(
    const float* __restrict__ x, const float* __restrict__ Wd,
    const float* __restrict__ bd, unsigned short* __restrict__ xb,
    float* __restrict__ decay,
    const float* __restrict__ Wb, const float* __restrict__ Wi,
    unsigned short* __restrict__ Wdst)
{
    int blk = blockIdx.x;
    int i   = threadIdx.x;
    if (blk >= M_ROWS) {
        // weight conversion: rows 0..767 = W_biv, 768..1535 = W_in
        const int NW = D_MODEL * D_MODEL;          // 589824
        int g = (blk - M_ROWS) * 256 + i;
        int base = g * 4;
        unsigned short* dst = Wdst + base;
        const float* src;
        if (base < NW) { src = Wb + base; }
        else           { src = Wi + (base - NW); }
        float4 v = *(const float4*)src;
        ushort4 o;
        o.x = f2bf(v.x); o.y = f2bf(v.y); o.z = f2bf(v.z); o.w = f2bf(v.w);
        *(ushort4*)dst = o;
        return;
    }
    int row = blk;
    const float* xr = x + (size_t)row * D_MODEL;
    float v0 = xr[i], v1 = xr[i + 256], v2 = xr[i + 512];
    unsigned short* xbr = xb + (size_t)row * D_MODEL;
    xbr[i] = f2bf(v0); xbr[i + 256] = f2bf(v1); xbr[i + 512] = f2bf(v2);

    float part = v0 * Wd[i] + v1 * Wd[i + 256] + v2 * Wd[i + 512];
    #pragma unroll
    for (int off = 32; off; off >>= 1) part += __shfl_down(part, off);
    __shared__ float wsum[4];
    int wid = i >> 6, lane = i & 63;
    if (lane == 0) wsum[wid] = part;
    __syncthreads();
    if (i == 0) {
        float s = wsum[0] + wsum[1] + wsum[2] + wsum[3] + bd[0];
        decay[row] = 1.f / (1.f + __expf(-s));
    }
}

// ---------------- Kernel 3: BARRIER-FREE tall-skinny GEMM ----------------
// C(M,1536) = A(M,768) * W(1536,768)^T + bias, quad-packed bf16 output.
// Block = 1024 rows x 64 cols; 8 waves x (128 rows x 64 cols).
// B-panel (64 x 768 = 96 KB) staged to LDS ONCE; K-loop has NO barriers:
// A-frags straight from global (L2-hot, 24x reuse), B-frags from LDS.
// 2-deep A register ring; prefetch for kt+2 issued AFTER step-kt MFMAs
// (WAR on the ring regs guarantees correctness; ~1.5 steps of latency cover).
#define GBM 1024
#define GBN 64
#define GNBX 24   // 1536/64
#define GNBY 32   // 32768/1024
#define NKT 24    // 768/32

__global__ __launch_bounds__(512) void k_gemm_fused(
    const unsigned short* __restrict__ A,    // (M,768) bf16 row-major
    const unsigned short* __restrict__ Bw,   // (1536,768) bf16 row-major
    const float* __restrict__ bias_biv, const float* __restrict__ bias_in,
    u32x2* __restrict__ bivq, u32x2* __restrict__ injq)
{
    extern __shared__ unsigned short LB[];   // [24 kt][64 col][32 k] = 96 KiB

    // XCD-chunked swizzle: 768 blocks, 96/XCD (4 M-panels x 24 N) -> A-panel L2 reuse
    int id  = blockIdx.x;
    int swz = (id & 7) * 96 + (id >> 3);
    int bxc = swz % GNBX, byr = swz / GNBX;
    int m0 = byr * GBM, n0 = bxc * GBN;

    int tid  = threadIdx.x;
    int w    = tid >> 6, lane = tid & 63;
    int rl = lane & 15, kq = lane >> 4;
    int sl = kq ^ ((rl >> 1) & 3);          // read-side 16B-slot XOR swizzle

    // ---- stage full B-panel to LDS (once) ----
    #pragma unroll
    for (int p = 0; p < 12; ++p) {
        int c    = p * 512 + tid;           // 16B chunk index, 0..6143
        int kt   = c >> 8;
        int rem  = c & 255;
        int col  = rem >> 2;
        int slot = rem & 3;
        int ssrc = slot ^ ((col >> 1) & 3); // pre-swizzled source (involution)
        gload_lds16(Bw + (size_t)(n0 + col) * D_MODEL + kt * 32 + ssrc * 8,
                    LB + c * 8);
    }
    __syncthreads();   // compiler inserts the vmcnt(0) drain before this

    // ---- free-running K-loop ----
    const unsigned short* Arow = A + (size_t)(m0 + w * 128 + rl) * D_MODEL + kq * 8;
    f32x4 acc[8][4] = {};
    bf16x8 afA[8], afB[8];

    #define LOADAF(RING, KT) do {                                                \
        _Pragma("unroll")                                                        \
        for (int i = 0; i < 8; ++i)                                              \
            RING[i] = *(const bf16x8*)(Arow + (size_t)i * 16 * D_MODEL + (KT) * 32); \
    } while (0)

    // consume RING at KT, then prefetch KT+2 into the SAME ring (now free)
    #define KSTEP(RING, KT) do {                                                 \
        bf16x8 bfv[4];                                                           \
        const unsigned short* pb = LB + (KT) * 2048 + rl * 32 + sl * 8;          \
        _Pragma("unroll")                                                        \
        for (int j = 0; j < 4; ++j) bfv[j] = *(const bf16x8*)(pb + j * 512);     \
        _Pragma("unroll")                                                        \
        for (int i = 0; i < 8; ++i)                                              \
            _Pragma("unroll")                                                    \
            for (int j = 0; j < 4; ++j)                                          \
                acc[i][j] = __builtin_amdgcn_mfma_f32_16x16x32_bf16(             \
                    RING[i], bfv[j], acc[i][j], 0, 0, 0);                        \
        if ((KT) + 2 < NKT) LOADAF(RING, (KT) + 2);                              \
    } while (0)

    LOADAF(afA, 0);
    LOADAF(afB, 1);
    #pragma unroll
    for (int kt = 0; kt < NKT; kt += 2) {
        KSTEP(afA, kt);
        KSTEP(afB, kt + 1);
    }
    #undef KSTEP
    #undef LOADAF

    // epilogue: quad-packed bf16 stores (rows quad-aligned), 32 x 8B per lane
    u32x2* Cq; const float* bias; int nloc;
    if (n0 < D_MODEL) { Cq = bivq; bias = bias_biv; nloc = n0; }
    else              { Cq = injq; bias = bias_in;  nloc = n0 - D_MODEL; }
    int qbase = (m0 >> 2) + w * 32 + kq;
    #pragma unroll
    for (int j = 0; j < 4; ++j) {
        int col = nloc + j * 16 + rl;
        float bs = bias[col];
        #pragma unroll
        for (int i = 0; i < 8; ++i) {
            f32x4 a = acc[i][j];
            unsigned int lo = (unsigned int)f2bf(a[0] + bs) | ((unsigned int)f2bf(a[1] + bs) << 16);
            unsigned int hi = (unsigned int)f2bf(a[2] + bs) | ((unsigned int)f2bf(a[3] + bs) << 16);
            u32x2 pk = {lo, hi};
            Cq[(size_t)(qbase + i * 4) * D_MODEL + col] = pk;
        }
    }
}

// ---------------- Scan step macros ----------------
#define QSTEP_CORE(BX,BY,BZ, IX,IY,IZ, DD)                              \
    {   float n2   = (BX)*(BX) + (BY)*(BY) + (BZ)*(BZ);                 \
        float nrm  = fmaxf(__builtin_sqrtf(n2), 1e-8f);                 \
        float half = 0.5f * nrm;                                        \
        float w = __cosf(half);                                         \
        float s = __sinf(half) / nrm;                                   \
        float qx = s * (BZ), qy = -s * (BY), qz = s * (BX);             \
        float tx = 2.f * (qy * hz - qz * hy);                           \
        float ty = 2.f * (qz * hx - qx * hz);                           \
        float tz = 2.f * (qx * hy - qy * hx);                           \
        float rx = hx + w * tx + (qy * tz - qz * ty);                   \
        float ry = hy + w * ty + (qz * tx - qx * tz);                   \
        float rz = hz + w * tz + (qx * ty - qy * tx);                   \
        hx = fmaf((DD), rx, (IX));                                      \
        hy = fmaf((DD), ry, (IY));                                      \
        hz = fmaf((DD), rz, (IZ));                                      \
        float nQw = w * Qw - qx * Qx - qy * Qy - qz * Qz;               \
        float nQx = w * Qx + Qw * qx + (qy * Qz - qz * Qy);             \
        float nQy = w * Qy + Qw * qy + (qz * Qx - qx * Qz);             \
        float nQz = w * Qz + Qw * qz + (qx * Qy - qy * Qx);             \
        Qw = nQw; Qx = nQx; Qy = nQy; Qz = nQz;                         \
        S *= (DD);                                                      \
    }

// recurrence-only step (no operator composition) for phase 3
#define QSTEP_H(BX,BY,BZ, IX,IY,IZ, DD)                                 \
    {   float n2   = (BX)*(BX) + (BY)*(BY) + (BZ)*(BZ);                 \
        float nrm  = fmaxf(__builtin_sqrtf(n2), 1e-8f);                 \
        float half = 0.5f * nrm;                                        \
        float w = __cosf(half);                                         \
        float s = __sinf(half) / nrm;                                   \
        float qx = s * (BZ), qy = -s * (BY), qz = s * (BX);             \
        float tx = 2.f * (qy * hz - qz * hy);                           \
        float ty = 2.f * (qz * hx - qx * hz);                           \
        float tz = 2.f * (qx * hy - qy * hx);                           \
        float rx = hx + w * tx + (qy * tz - qz * ty);                   \
        float ry = hy + w * ty + (qz * tx - qx * tz);                   \
        float rz = hz + w * tz + (qx * ty - qy * tx);                   \
        hx = fmaf((DD), rx, (IX));                                      \
        hy = fmaf((DD), ry, (IY));                                      \
        hz = fmaf((DD), rz, (IZ));                                      \
    }

// ---------------- Scan phase 1: per-(chain,chunk) operator compose (quad-packed reads) ----
__global__ __launch_bounds__(256) void k_scan_p1(
    const u32x2* __restrict__ bivq, const u32x2* __restrict__ injq,
    const float* __restrict__ decay,
    float* __restrict__ ops)          // per (b,c,j): {Qw,Qx,Qy,Qz,S,bx,by,bz}
{
    int j = threadIdx.x;
    int c = blockIdx.x & (CHUNKS - 1);
    int b = blockIdx.x >> 6;
    size_t qrow = ((size_t)b * SEQ + (size_t)c * CLEN) >> 2;
    const u32x2* bv = bivq + qrow * D_MODEL + 3 * j;
    const u32x2* ij = injq + qrow * D_MODEL + 3 * j;
    const float* dk = decay + (size_t)b * SEQ + c * CLEN;

    u32x2 Ab0, Ab1, Ab2, Ai0, Ai1, Ai2; f32x4 Ad;
    u32x2 Bb0, Bb1, Bb2, Bi0, Bi1, Bi2; f32x4 Bd;

    #define LOADQ1(P, q)                                                  \
        P##b0 = bv[(size_t)(q) * D_MODEL + 0];                            \
        P##b1 = bv[(size_t)(q) * D_MODEL + 1];                            \
        P##b2 = bv[(size_t)(q) * D_MODEL + 2];                            \
        P##i0 = ij[(size_t)(q) * D_MODEL + 0];                            \
        P##i1 = ij[(size_t)(q) * D_MODEL + 1];                            \
        P##i2 = ij[(size_t)(q) * D_MODEL + 2];                            \
        P##d  = *(const f32x4*)(dk + (q) * 4);

    #define PROC41(P)                                                     \
        _Pragma("unroll")                                                 \
        for (int k = 0; k < 4; ++k) {                                     \
            float bx = bfx(P##b0, k), by = bfx(P##b1, k), bz = bfx(P##b2, k); \
            float ix = bfx(P##i0, k), iy = bfx(P##i1, k), iz = bfx(P##i2, k); \
            float d = P##d[k];                                            \
            QSTEP_CORE(bx, by, bz, ix, iy, iz, d)                         \
        }

    float hx = 0.f, hy = 0.f, hz = 0.f;
    float Qw = 1.f, Qx = 0.f, Qy = 0.f, Qz = 0.f, S = 1.f;

    LOADQ1(A, 0)
    LOADQ1(B, 1)
    #pragma unroll
    for (int q0 = 0; q0 < CLEN / 4; q0 += 2) {
        PROC41(A)
        if (q0 + 2 < CLEN / 4) { LOADQ1(A, q0 + 2) }
        PROC41(B)
        if (q0 + 3 < CLEN / 4) { LOADQ1(B, q0 + 3) }
    }
    #undef LOADQ1
    #undef PROC41

    float* op = ops + ((size_t)(b * CHUNKS + c) * 256 + j) * 8;
    f32x4 o0 = {Qw, Qx, Qy, Qz};
    f32x4 o1 = {S, hx, hy, hz};
    *(f32x4*)op = o0;
    *(f32x4*)(op + 4) = o1;
}

// ---------------- Scan phase 2: sequential fold of 64 chunk operators per chain ----------------
__global__ __launch_bounds__(64) void k_scan_p2(
    const float* __restrict__ ops, unsigned short* __restrict__ hsb)
{
    int gid = blockIdx.x * 64 + threadIdx.x;   // 0..4095
    int j = gid & 255, b = gid >> 8;

    float q0[PFB], q1[PFB], q2[PFB], q3[PFB], sc[PFB], o0[PFB], o1[PFB], o2[PFB];
    #pragma unroll
    for (int p = 0; p < PFB; ++p) {
        const float* op = ops + ((size_t)(b * CHUNKS + p) * 256 + j) * 8;
        f32x4 a = *(const f32x4*)op, bb = *(const f32x4*)(op + 4);
        q0[p] = a[0]; q1[p] = a[1]; q2[p] = a[2]; q3[p] = a[3];
        sc[p] = bb[0]; o0[p] = bb[1]; o1[p] = bb[2]; o2[p] = bb[3];
    }
    float hx = 0.f, hy = 0.f, hz = 0.f;
    for (int c0 = 0; c0 < CHUNKS; c0 += PFB) {
        #pragma unroll
        for (int p = 0; p < PFB; ++p) {
            int c = c0 + p;
            unsigned short* h = hsb + ((size_t)(b * CHUNKS + c) * 256 + j) * 3;
            h[0] = f2bf(hx); h[1] = f2bf(hy); h[2] = f2bf(hz);   // h at entry of chunk c
            float w = q0[p], qx = q1[p], qy = q2[p], qz = q3[p];
            float s = sc[p], bx = o0[p], by = o1[p], bz = o2[p];
            int cn = c + PFB;
            if (cn < CHUNKS) {
                const float* op = ops + ((size_t)(b * CHUNKS + cn) * 256 + j) * 8;
                f32x4 a = *(const f32x4*)op, bb = *(const f32x4*)(op + 4);
                q0[p] = a[0]; q1[p] = a[1]; q2[p] = a[2]; q3[p] = a[3];
                sc[p] = bb[0]; o0[p] = bb[1]; o1[p] = bb[2]; o2[p] = bb[3];
            }
            float tx = 2.f * (qy * hz - qz * hy);
            float ty = 2.f * (qz * hx - qx * hz);
            float tz = 2.f * (qx * hy - qy * hx);
            float rx = hx + w * tx + (qy * tz - qz * ty);
            float ry = hy + w * ty + (qz * tx - qx * tz);
            float rz = hz + w * tz + (qx * ty - qy * tx);
            hx = fmaf(s, rx, bx);
            hy = fmaf(s, ry, by);
            hz = fmaf(s, rz, bz);
        }
    }
}

// ---------------- Scan phase 3: recurrence -> 16-step LDS halves, ping-pong with parallel LN ----
__global__ __launch_bounds__(256) void k_scan_p3(
    const u32x2* __restrict__ bivq, const u32x2* __restrict__ injq,
    const float* __restrict__ decay, const unsigned short* __restrict__ hsb,
    const unsigned short* __restrict__ xb, const float* __restrict__ gamma,
    const float* __restrict__ beta, float* __restrict__ out)
{
    int blk = blockIdx.x;
    int c = blk & (CHUNKS - 1);
    int b = blk >> 6;
    int j = threadIdx.x;
    size_t row0 = (size_t)b * SEQ + (size_t)c * CLEN;
    size_t qrow = row0 >> 2;
    const u32x2* bv = bivq + qrow * D_MODEL + 3 * j;
    const u32x2* ij = injq + qrow * D_MODEL + 3 * j;
    const float* dk = decay + row0;
    const unsigned short* h0p = hsb + ((size_t)(b * CHUNKS + c) * 256 + j) * 3;
    float hx = bf2f(h0p[0]), hy = bf2f(h0p[1]), hz = bf2f(h0p[2]);

    __shared__ uint32_t       hxyS[16 * 256];   // 16 KiB: (hx,hy) bf16-packed, half-buffer
    __shared__ unsigned short hzS [16 * 256];   //  8 KiB

    int wid = j >> 6, lane = j & 63;
    const float4* g4 = (const float4*)(gamma + lane * 12);
    const float4* e4 = (const float4*)(beta  + lane * 12);
    float4 G0 = g4[0], G1 = g4[1], G2 = g4[2];
    float4 E0 = e4[0], E1 = e4[1], E2 = e4[2];
    const unsigned short* xbase = xb  + row0 * D_MODEL;
    float*                obase = out + row0 * D_MODEL;

    auto LN_HALF = [&](int H) {
        #pragma unroll
        for (int r = wid; r < 16; r += 4) {
            uint4   hv = *(const uint4*)  &hxyS[r * 256 + 4 * lane];
            ushort4 zv = *(const ushort4*)&hzS [r * 256 + 4 * lane];
            float h[12];
            h[0]  = bf2f((unsigned short)(hv.x & 0xFFFF)); h[1]  = bf2f((unsigned short)(hv.x >> 16)); h[2]  = bf2f(zv.x);
            h[3]  = bf2f((unsigned short)(hv.y & 0xFFFF)); h[4]  = bf2f((unsigned short)(hv.y >> 16)); h[5]  = bf2f(zv.y);
            h[6]  = bf2f((unsigned short)(hv.z & 0xFFFF)); h[7]  = bf2f((unsigned short)(hv.z >> 16)); h[8]  = bf2f(zv.z);
            h[9]  = bf2f((unsigned short)(hv.w & 0xFFFF)); h[10] = bf2f((unsigned short)(hv.w >> 16)); h[11] = bf2f(zv.w);
            float sp = 0.f, qp = 0.f;
            #pragma unroll
            for (int k = 0; k < 12; ++k) { sp += h[k]; qp += h[k] * h[k]; }
            #pragma unroll
            for (int off = 1; off < 64; off <<= 1) {
                sp += __shfl_xor(sp, off);
                qp += __shfl_xor(qp, off);
            }
            float mean = sp * (1.f / 768.f);
            float var  = qp * (1.f / 768.f) - mean * mean;
            float rstd = rsqrtf(var + LN_EPS);

            int t = H * 16 + r;
            const unsigned short* xr2 = xbase + (size_t)t * D_MODEL + lane * 12;
            float*                or2 = obase + (size_t)t * D_MODEL + lane * 12;
            ushort4 Xa = *(const ushort4*)(xr2 + 0);
            ushort4 Xb = *(const ushort4*)(xr2 + 4);
            ushort4 Xc = *(const ushort4*)(xr2 + 8);
            float4 O0, O1, O2;
            O0.x = (h[0]  - mean) * rstd * G0.x + E0.x + bf2f(Xa.x);
            O0.y = (h[1]  - mean) * rstd * G0.y + E0.y + bf2f(Xa.y);
            O0.z = (h[2]  - mean) * rstd * G0.z + E0.z + bf2f(Xa.z);
            O0.w = (h[3]  - mean) * rstd * G0.w + E0.w + bf2f(Xa.w);
            O1.x = (h[4]  - mean) * rstd * G1.x + E1.x + bf2f(Xb.x);
            O1.y = (h[5]  - mean) * rstd * G1.y + E1.y + bf2f(Xb.y);
            O1.z = (h[6]  - mean) * rstd * G1.z + E1.z + bf2f(Xb.z);
            O1.w = (h[7]  - mean) * rstd * G1.w + E1.w + bf2f(Xb.w);
            O2.x = (h[8]  - mean) * rstd * G2.x + E2.x + bf2f(Xc.x);
            O2.y = (h[9]  - mean) * rstd * G2.y + E2.y + bf2f(Xc.y);
            O2.z = (h[10] - mean) * rstd * G2.z + E2.z + bf2f(Xc.z);
            O2.w = (h[11] - mean) * rstd * G2.w + E2.w + bf2f(Xc.w);
            *(float4*)(or2 + 0) = O0;
            *(float4*)(or2 + 4) = O1;
            *(float4*)(or2 + 8) = O2;
        }
    };

    u32x2 Ab0, Ab1, Ab2, Ai0, Ai1, Ai2; f32x4 Ad;
    u32x2 Bb0, Bb1, Bb2, Bi0, Bi1, Bi2; f32x4 Bd;

    #define LOADQH(P, q)                                                  \
        P##b0 = bv[(size_t)(q) * D_MODEL + 0];                            \
        P##b1 = bv[(size_t)(q) * D_MODEL + 1];                            \
        P##b2 = bv[(size_t)(q) * D_MODEL + 2];                            \
        P##i0 = ij[(size_t)(q) * D_MODEL + 0];                            \
        P##i1 = ij[(size_t)(q) * D_MODEL + 1];                            \
        P##i2 = ij[(size_t)(q) * D_MODEL + 2];                            \
        P##d  = *(const f32x4*)(dk + (q) * 4);

    // store at half-relative slot ((QBASE*4+k) & 15)
    #define PROC4H(P, QBASE)                                              \
        _Pragma("unroll")                                                 \
        for (int k = 0; k < 4; ++k) {                                     \
            float bx = bfx(P##b0, k), by = bfx(P##b1, k), bz = bfx(P##b2, k); \
            float ix = bfx(P##i0, k), iy = bfx(P##i1, k), iz = bfx(P##i2, k); \
            float d = P##d[k];                                            \
            QSTEP_H(bx, by, bz, ix, iy, iz, d)                            \
            int tt = (((QBASE) * 4 + k) & 15);                            \
            hxyS[tt * 256 + j] = (uint32_t)f2bf(hx) | ((uint32_t)f2bf(hy) << 16); \
            hzS [tt * 256 + j] = f2bf(hz);                                \
        }

    LOADQH(A, 0)
    LOADQH(B, 1)
    // half 0: quads 0..3 (steps 0..15); prefetch half-1 quads before the barrier
    PROC4H(A, 0) LOADQH(A, 2)
    PROC4H(B, 1) LOADQH(B, 3)
    PROC4H(A, 2) LOADQH(A, 4)
    PROC4H(B, 3) LOADQH(B, 5)
    __syncthreads();
    LN_HALF(0);                    // half-1 global loads in flight under the LN
    __syncthreads();
    // half 1: quads 4..7 (steps 16..31)
    PROC4H(A, 4) LOADQH(A, 6)
    PROC4H(B, 5) LOADQH(B, 7)
    PROC4H(A, 6)
    PROC4H(B, 7)
    __syncthreads();
    LN_HALF(1);

    #undef LOADQH
    #undef PROC4H
}

extern "C" void kernel_launch(void* const* d_in, const int* in_sizes, int n_in,
                              void* d_out, int out_size, void* d_ws, size_t ws_size,
                              hipStream_t stream) {
    const float* x     = (const float*)d_in[0];
    const float* W_biv = (const float*)d_in[1];
    const float* b_biv = (const float*)d_in[2];
    const float* W_dec = (const float*)d_in[3];
    const float* b_dec = (const float*)d_in[4];
    const float* W_in  = (const float*)d_in[5];
    const float* b_in  = (const float*)d_in[6];
    const float* gamma = (const float*)d_in[7];
    const float* beta  = (const float*)d_in[8];
    float* out = (float*)d_out;

    // workspace layout (153.5 MB); xb stays ALIVE through p3 (residual source)
    char* ws = (char*)d_ws;
    unsigned short* xb    = (unsigned short*)(ws);               // 50,331,648 B
    unsigned short* Wcat  = (unsigned short*)(ws + 50331648);    //  2,359,296 B (dead after GEMM)
    float*          decay = (float*)         (ws + 52690944);    //    131,072 B
    u32x2*          bivq  = (u32x2*)         (ws + 52822016);    // 50,331,648 B (quad-packed bf16)
    u32x2*          injq  = (u32x2*)         (ws + 103153664);   // 50,331,648 B (quad-packed bf16)
    // ops lives in d_out (used only between p1 and p2; p3 overwrites d_out later)
    float*          ops   = (float*)d_out;                       //  8,388,608 B
    // hs (bf16) reuses the dead Wcat region
    unsigned short* hsb   = (unsigned short*)(ws + 50331648);    //  1,572,864 B

    (void)in_sizes; (void)n_in; (void)out_size; (void)ws_size;

    // allow 96 KiB dynamic LDS for the GEMM (host-side attribute, graph-capture-safe)
    hipFuncSetAttribute((const void*)k_gemm_fused,
                        hipFuncAttributeMaxDynamicSharedMemorySize, 98304);

    k_conv      <<<M_ROWS + 1152, 256, 0, stream>>>(x, W_dec, b_dec, xb, decay, W_biv, W_in, Wcat);
    k_gemm_fused<<<GNBX * GNBY, 512, 98304, stream>>>(xb, Wcat, b_biv, b_in, bivq, injq);
    k_scan_p1   <<<1024, 256, 0, stream>>>(bivq, injq, decay, ops);
    k_scan_p2   <<<64,   64,  0, stream>>>(ops, hsb);
    k_scan_p3   <<<1024, 256, 0, stream>>>(bivq, injq, decay, hsb, xb, gamma, beta, out);
}

// Round 14
// 206.604 us; speedup vs baseline: 1.5027x; 1.5027x over previous
//
#include <hip/hip_runtime.h>
#include <stdint.h>

#define D_MODEL 768
#define BATCH   16
#define SEQ     2048
#define M_ROWS  (BATCH * SEQ)   // 32768
#define LN_EPS  1e-5f

#define CHUNKS  64
#define CLEN    (SEQ / CHUNKS)  // 32
#define PFB     8               // prefetch depth, phase 2

typedef __attribute__((ext_vector_type(4))) float        f32x4;
typedef __attribute__((ext_vector_type(8))) __bf16       bf16x8;
typedef __attribute__((ext_vector_type(2))) unsigned int u32x2;

__device__ __forceinline__ unsigned short f2bf(float f) {
    union { float f; uint32_t u; } v; v.f = f;
    uint32_t u = v.u;
    uint32_t r = (u + 0x7FFFu + ((u >> 16) & 1u)) >> 16;   // RNE
    return (unsigned short)r;
}
__device__ __forceinline__ float bf2f(unsigned short u) {
    union { uint32_t u; float f; } v; v.u = (uint32_t)u << 16; return v.f;
}
// extract element k (0..3) of a packed quad (4 bf16 in 8B)
__device__ __forceinline__ float bfx(u32x2 v, int k) {
    unsigned int w = (k & 2) ? v[1] : v[0];
    return bf2f((unsigned short)(w >> ((k & 1) * 16)));
}

__device__ __forceinline__ void gload_lds16(const void* g, void* l) {
    __builtin_amdgcn_global_load_lds(
        (const __attribute__((address_space(1))) unsigned int*)g,
        (__attribute__((address_space(3))) unsigned int*)l,
        16, 0, 0);
}

// ---------------- Kernel 1: x->bf16 + decay GEMV, and W->bf16 (merged, block-uniform split) ----
__global__ __launch_bounds__(256) void k_conv(
    const float* __restrict__ x, const float* __restrict__ Wd,
    const float* __restrict__ bd, unsigned short* __restrict__ xb,
    float* __restrict__ decay,
    const float* __restrict__ Wb, const float* __restrict__ Wi,
    unsigned short* __restrict__ Wdst)
{
    int blk = blockIdx.x;
    int i   = threadIdx.x;
    if (blk >= M_ROWS) {
        // weight conversion: rows 0..767 = W_biv, 768..1535 = W_in
        const int NW = D_MODEL * D_MODEL;          // 589824
        int g = (blk - M_ROWS) * 256 + i;
        int base = g * 4;
        unsigned short* dst = Wdst + base;
        const float* src;
        if (base < NW) { src = Wb + base; }
        else           { src = Wi + (base - NW); }
        float4 v = *(const float4*)src;
        ushort4 o;
        o.x = f2bf(v.x); o.y = f2bf(v.y); o.z = f2bf(v.z); o.w = f2bf(v.w);
        *(ushort4*)dst = o;
        return;
    }
    int row = blk;
    const float* xr = x + (size_t)row * D_MODEL;
    float v0 = xr[i], v1 = xr[i + 256], v2 = xr[i + 512];
    unsigned short* xbr = xb + (size_t)row * D_MODEL;
    xbr[i] = f2bf(v0); xbr[i + 256] = f2bf(v1); xbr[i + 512] = f2bf(v2);

    float part = v0 * Wd[i] + v1 * Wd[i + 256] + v2 * Wd[i + 512];
    #pragma unroll
    for (int off = 32; off; off >>= 1) part += __shfl_down(part, off);
    __shared__ float wsum[4];
    int wid = i >> 6, lane = i & 63;
    if (lane == 0) wsum[wid] = part;
    __syncthreads();
    if (i == 0) {
        float s = wsum[0] + wsum[1] + wsum[2] + wsum[3] + bd[0];
        decay[row] = 1.f / (1.f + __expf(-s));
    }
}

// ---------------- Kernel 3: 256x256 bf16 MFMA GEMM, 4 sub-phases/K-tile ----------
// C(M,1536) = A(M,768) * W(1536,768)^T + bias, quad-packed bf16 output.
#define GBM 256
#define GBN 256
#define GNBX 6    // 1536/256
#define GNBY 128  // 32768/256

__global__ __launch_bounds__(512, 2) void k_gemm_fused(
    const unsigned short* __restrict__ A,    // (M,768) bf16 row-major
    const unsigned short* __restrict__ Bw,   // (1536,768) bf16 row-major
    const float* __restrict__ bias_biv, const float* __restrict__ bias_in,
    u32x2* __restrict__ bivq, u32x2* __restrict__ injq)
{
    extern __shared__ unsigned short LDSBUF[];
    unsigned short* LA = LDSBUF;            // [2 buf][2 H][256 row][32 col] = 65536 B
    unsigned short* LB = LDSBUF + 32768;    // same, 65536 B

    // XCD-chunked swizzle: 768 blocks, 96 per XCD (16 M-panels x 6 N) -> A-panel L2 reuse
    int id  = blockIdx.x;
    int swz = (id & 7) * 96 + (id >> 3);
    int bxc = swz % GNBX, byr = swz / GNBX;
    int m0 = byr * GBM, n0 = bxc * GBN;

    int tid  = threadIdx.x;
    int wid  = tid >> 6, lane = tid & 63;
    int wm = wid >> 2, wn = wid & 3;        // 2x4 wave grid; wave tile 128x64
    int rl = lane & 15, kq = lane >> 4;
    int sl = kq ^ ((rl >> 1) & 3);          // read-side 16B-slot XOR swizzle
    int aoff = (wm * 128 + rl) * 32 + sl * 8;   // ushort offset within an H-block
    int boff = (wn * 64  + rl) * 32 + sl * 8;

    f32x4 acc[8][4] = {};
    bf16x8 bfv[4];

    // stage one unit: (H, RH) = 32 K-cols x 128 rows of A and B (2 gloads/thread)
    #define STAGE_UNIT(DBUF, KT, H, RH) do {                                     \
        int idx = (RH) * 512 + tid;                                              \
        int row = idx >> 2;                                                      \
        int ss  = ((idx & 3) ^ ((idx >> 3) & 3)) * 8;  /* pre-swizzled src */    \
        gload_lds16(A  + (size_t)(m0 + row) * D_MODEL + (KT) * 64 + (H) * 32 + ss, \
                    LA + (DBUF) * 16384 + (H) * 8192 + idx * 8);                 \
        gload_lds16(Bw + (size_t)(n0 + row) * D_MODEL + (KT) * 64 + (H) * 32 + ss, \
                    LB + (DBUF) * 16384 + (H) * 8192 + idx * 8);                 \
    } while (0)

    #define SUBPHASE(D, H, MH, DOSTAGE, SKT, SH, SRH, WAITSTR) do {              \
        const unsigned short* pa = LA + (D) * 16384 + (H) * 8192 + aoff + (MH) * 2048; \
        const unsigned short* pb = LB + (D) * 16384 + (H) * 8192 + boff;         \
        bf16x8 af[4];                                                            \
        _Pragma("unroll")                                                        \
        for (int i = 0; i < 4; ++i) af[i] = *(const bf16x8*)(pa + i * 512);      \
        if ((MH) == 0) {                                                         \
            _Pragma("unroll")                                                    \
            for (int j = 0; j < 4; ++j) bfv[j] = *(const bf16x8*)(pb + j * 512); \
        }                                                                        \
        if (DOSTAGE) STAGE_UNIT((D) ^ 1, SKT, SH, SRH);                          \
        asm volatile(WAITSTR ::: "memory");                                      \
        asm volatile("s_barrier" ::: "memory");                                  \
        asm volatile("s_waitcnt lgkmcnt(0)" ::: "memory");                       \
        __builtin_amdgcn_sched_barrier(0);                                       \
        __builtin_amdgcn_s_setprio(1);                                           \
        _Pragma("unroll")                                                        \
        for (int i = 0; i < 4; ++i)                                              \
            _Pragma("unroll")                                                    \
            for (int j = 0; j < 4; ++j)                                          \
                acc[(MH) * 4 + i][j] = __builtin_amdgcn_mfma_f32_16x16x32_bf16(  \
                    af[i], bfv[j], acc[(MH) * 4 + i][j], 0, 0, 0);               \
        __builtin_amdgcn_s_setprio(0);                                           \
        asm volatile("s_barrier" ::: "memory");                                  \
    } while (0)

    // prologue: stage kt0 fully (8 gloads/wave); certify H0 (leave u2,u3 in flight)
    STAGE_UNIT(0, 0, 0, 0);
    STAGE_UNIT(0, 0, 0, 1);
    STAGE_UNIT(0, 0, 1, 0);
    STAGE_UNIT(0, 0, 1, 1);
    asm volatile("s_waitcnt vmcnt(4)" ::: "memory");
    asm volatile("s_barrier" ::: "memory");

    for (int kt = 0; kt < 10; ++kt) {
        int D = kt & 1;
        SUBPHASE(D, 0, 0, true, kt + 1, 0, 0, "");
        SUBPHASE(D, 0, 1, true, kt + 1, 0, 1, "s_waitcnt vmcnt(4)");  // certify this kt H1
        SUBPHASE(D, 1, 0, true, kt + 1, 1, 0, "");
        SUBPHASE(D, 1, 1, true, kt + 1, 1, 1, "s_waitcnt vmcnt(4)");  // certify next kt H0
    }
    // kt = 10 (buf 0), staging kt 11
    SUBPHASE(0, 0, 0, true, 11, 0, 0, "");
    SUBPHASE(0, 0, 1, true, 11, 0, 1, "s_waitcnt vmcnt(4)");
    SUBPHASE(0, 1, 0, true, 11, 1, 0, "");
    SUBPHASE(0, 1, 1, true, 11, 1, 1, "s_waitcnt vmcnt(4)");
    // kt = 11 (buf 1), no staging
    SUBPHASE(1, 0, 0, false, 0, 0, 0, "");
    SUBPHASE(1, 0, 1, false, 0, 0, 0, "s_waitcnt vmcnt(0)");
    SUBPHASE(1, 1, 0, false, 0, 0, 0, "");
    SUBPHASE(1, 1, 1, false, 0, 0, 0, "");

    #undef SUBPHASE
    #undef STAGE_UNIT

    // epilogue: quad-packed bf16 stores (rows quad-aligned), 32 x 8B per lane
    u32x2* Cq; const float* bias; int nloc;
    if (n0 < D_MODEL) { Cq = bivq; bias = bias_biv; nloc = n0; }
    else              { Cq = injq; bias = bias_in;  nloc = n0 - D_MODEL; }
    int cl = lane & 15;
    int qbase = (m0 >> 2) + wm * 32 + (lane >> 4);
    #pragma unroll
    for (int j = 0; j < 4; ++j) {
        int col = nloc + wn * 64 + j * 16 + cl;
        float bs = bias[col];
        #pragma unroll
        for (int i = 0; i < 8; ++i) {
            f32x4 a = acc[i][j];
            unsigned int lo = (unsigned int)f2bf(a[0] + bs) | ((unsigned int)f2bf(a[1] + bs) << 16);
            unsigned int hi = (unsigned int)f2bf(a[2] + bs) | ((unsigned int)f2bf(a[3] + bs) << 16);
            u32x2 pk = {lo, hi};
            Cq[(size_t)(qbase + i * 4) * D_MODEL + col] = pk;
        }
    }
}

// ---------------- Scan step macros ----------------
#define QSTEP_CORE(BX,BY,BZ, IX,IY,IZ, DD)                              \
    {   float n2   = (BX)*(BX) + (BY)*(BY) + (BZ)*(BZ);                 \
        float nrm  = fmaxf(__builtin_sqrtf(n2), 1e-8f);                 \
        float half = 0.5f * nrm;                                        \
        float w = __cosf(half);                                         \
        float s = __sinf(half) / nrm;                                   \
        float qx = s * (BZ), qy = -s * (BY), qz = s * (BX);             \
        float tx = 2.f * (qy * hz - qz * hy);                           \
        float ty = 2.f * (qz * hx - qx * hz);                           \
        float tz = 2.f * (qx * hy - qy * hx);                           \
        float rx = hx + w * tx + (qy * tz - qz * ty);                   \
        float ry = hy + w * ty + (qz * tx - qx * tz);                   \
        float rz = hz + w * tz + (qx * ty - qy * tx);                   \
        hx = fmaf((DD), rx, (IX));                                      \
        hy = fmaf((DD), ry, (IY));                                      \
        hz = fmaf((DD), rz, (IZ));                                      \
        float nQw = w * Qw - qx * Qx - qy * Qy - qz * Qz;               \
        float nQx = w * Qx + Qw * qx + (qy * Qz - qz * Qy);             \
        float nQy = w * Qy + Qw * qy + (qz * Qx - qx * Qz);             \
        float nQz = w * Qz + Qw * qz + (qx * Qy - qy * Qx);             \
        Qw = nQw; Qx = nQx; Qy = nQy; Qz = nQz;                         \
        S *= (DD);                                                      \
    }

// recurrence-only step (no operator composition) for phase 3
#define QSTEP_H(BX,BY,BZ, IX,IY,IZ, DD)                                 \
    {   float n2   = (BX)*(BX) + (BY)*(BY) + (BZ)*(BZ);                 \
        float nrm  = fmaxf(__builtin_sqrtf(n2), 1e-8f);                 \
        float half = 0.5f * nrm;                                        \
        float w = __cosf(half);                                         \
        float s = __sinf(half) / nrm;                                   \
        float qx = s * (BZ), qy = -s * (BY), qz = s * (BX);             \
        float tx = 2.f * (qy * hz - qz * hy);                           \
        float ty = 2.f * (qz * hx - qx * hz);                           \
        float tz = 2.f * (qx * hy - qy * hx);                           \
        float rx = hx + w * tx + (qy * tz - qz * ty);                   \
        float ry = hy + w * ty + (qz * tx - qx * tz);                   \
        float rz = hz + w * tz + (qx * ty - qy * tx);                   \
        hx = fmaf((DD), rx, (IX));                                      \
        hy = fmaf((DD), ry, (IY));                                      \
        hz = fmaf((DD), rz, (IZ));                                      \
    }

// ---------------- Scan phase 1: per-(chain,chunk) operator compose (quad-packed reads) ----
__global__ __launch_bounds__(256) void k_scan_p1(
    const u32x2* __restrict__ bivq, const u32x2* __restrict__ injq,
    const float* __restrict__ decay,
    float* __restrict__ ops)          // per (b,c,j): {Qw,Qx,Qy,Qz,S,bx,by,bz}
{
    int j = threadIdx.x;
    int c = blockIdx.x & (CHUNKS - 1);
    int b = blockIdx.x >> 6;
    size_t qrow = ((size_t)b * SEQ + (size_t)c * CLEN) >> 2;
    const u32x2* bv = bivq + qrow * D_MODEL + 3 * j;
    const u32x2* ij = injq + qrow * D_MODEL + 3 * j;
    const float* dk = decay + (size_t)b * SEQ + c * CLEN;

    u32x2 Ab0, Ab1, Ab2, Ai0, Ai1, Ai2; f32x4 Ad;
    u32x2 Bb0, Bb1, Bb2, Bi0, Bi1, Bi2; f32x4 Bd;

    #define LOADQ1(P, q)                                                  \
        P##b0 = bv[(size_t)(q) * D_MODEL + 0];                            \
        P##b1 = bv[(size_t)(q) * D_MODEL + 1];                            \
        P##b2 = bv[(size_t)(q) * D_MODEL + 2];                            \
        P##i0 = ij[(size_t)(q) * D_MODEL + 0];                            \
        P##i1 = ij[(size_t)(q) * D_MODEL + 1];                            \
        P##i2 = ij[(size_t)(q) * D_MODEL + 2];                            \
        P##d  = *(const f32x4*)(dk + (q) * 4);

    #define PROC41(P)                                                     \
        _Pragma("unroll")                                                 \
        for (int k = 0; k < 4; ++k) {                                     \
            float bx = bfx(P##b0, k), by = bfx(P##b1, k), bz = bfx(P##b2, k); \
            float ix = bfx(P##i0, k), iy = bfx(P##i1, k), iz = bfx(P##i2, k); \
            float d = P##d[k];                                            \
            QSTEP_CORE(bx, by, bz, ix, iy, iz, d)                         \
        }

    float hx = 0.f, hy = 0.f, hz = 0.f;
    float Qw = 1.f, Qx = 0.f, Qy = 0.f, Qz = 0.f, S = 1.f;

    LOADQ1(A, 0)
    LOADQ1(B, 1)
    #pragma unroll
    for (int q0 = 0; q0 < CLEN / 4; q0 += 2) {
        PROC41(A)
        if (q0 + 2 < CLEN / 4) { LOADQ1(A, q0 + 2) }
        PROC41(B)
        if (q0 + 3 < CLEN / 4) { LOADQ1(B, q0 + 3) }
    }
    #undef LOADQ1
    #undef PROC41

    float* op = ops + ((size_t)(b * CHUNKS + c) * 256 + j) * 8;
    f32x4 o0 = {Qw, Qx, Qy, Qz};
    f32x4 o1 = {S, hx, hy, hz};
    *(f32x4*)op = o0;
    *(f32x4*)(op + 4) = o1;
}

// ---------------- Scan phase 2: sequential fold of 64 chunk operators per chain ----------------
__global__ __launch_bounds__(64) void k_scan_p2(
    const float* __restrict__ ops, unsigned short* __restrict__ hsb)
{
    int gid = blockIdx.x * 64 + threadIdx.x;   // 0..4095
    int j = gid & 255, b = gid >> 8;

    float q0[PFB], q1[PFB], q2[PFB], q3[PFB], sc[PFB], o0[PFB], o1[PFB], o2[PFB];
    #pragma unroll
    for (int p = 0; p < PFB; ++p) {
        const float* op = ops + ((size_t)(b * CHUNKS + p) * 256 + j) * 8;
        f32x4 a = *(const f32x4*)op, bb = *(const f32x4*)(op + 4);
        q0[p] = a[0]; q1[p] = a[1]; q2[p] = a[2]; q3[p] = a[3];
        sc[p] = bb[0]; o0[p] = bb[1]; o1[p] = bb[2]; o2[p] = bb[3];
    }
    float hx = 0.f, hy = 0.f, hz = 0.f;
    for (int c0 = 0; c0 < CHUNKS; c0 += PFB) {
        #pragma unroll
        for (int p = 0; p < PFB; ++p) {
            int c = c0 + p;
            unsigned short* h = hsb + ((size_t)(b * CHUNKS + c) * 256 + j) * 3;
            h[0] = f2bf(hx); h[1] = f2bf(hy); h[2] = f2bf(hz);   // h at entry of chunk c
            float w = q0[p], qx = q1[p], qy = q2[p], qz = q3[p];
            float s = sc[p], bx = o0[p], by = o1[p], bz = o2[p];
            int cn = c + PFB;
            if (cn < CHUNKS) {
                const float* op = ops + ((size_t)(b * CHUNKS + cn) * 256 + j) * 8;
                f32x4 a = *(const f32x4*)op, bb = *(const f32x4*)(op + 4);
                q0[p] = a[0]; q1[p] = a[1]; q2[p] = a[2]; q3[p] = a[3];
                sc[p] = bb[0]; o0[p] = bb[1]; o1[p] = bb[2]; o2[p] = bb[3];
            }
            float tx = 2.f * (qy * hz - qz * hy);
            float ty = 2.f * (qz * hx - qx * hz);
            float tz = 2.f * (qx * hy - qy * hx);
            float rx = hx + w * tx + (qy * tz - qz * ty);
            float ry = hy + w * ty + (qz * tx - qx * tz);
            float rz = hz + w * tz + (qx * ty - qy * tx);
            hx = fmaf(s, rx, bx);
            hy = fmaf(s, ry, by);
            hz = fmaf(s, rz, bz);
        }
    }
}

// ---------------- Scan phase 3: recurrence -> 16-step LDS halves, ping-pong with parallel LN ----
__global__ __launch_bounds__(256) void k_scan_p3(
    const u32x2* __restrict__ bivq, const u32x2* __restrict__ injq,
    const float* __restrict__ decay, const unsigned short* __restrict__ hsb,
    const unsigned short* __restrict__ xb, const float* __restrict__ gamma,
    const float* __restrict__ beta, float* __restrict__ out)
{
    int blk = blockIdx.x;
    int c = blk & (CHUNKS - 1);
    int b = blk >> 6;
    int j = threadIdx.x;
    size_t row0 = (size_t)b * SEQ + (size_t)c * CLEN;
    size_t qrow = row0 >> 2;
    const u32x2* bv = bivq + qrow * D_MODEL + 3 * j;
    const u32x2* ij = injq + qrow * D_MODEL + 3 * j;
    const float* dk = decay + row0;
    const unsigned short* h0p = hsb + ((size_t)(b * CHUNKS + c) * 256 + j) * 3;
    float hx = bf2f(h0p[0]), hy = bf2f(h0p[1]), hz = bf2f(h0p[2]);

    __shared__ uint32_t       hxyS[16 * 256];   // 16 KiB: (hx,hy) bf16-packed, half-buffer
    __shared__ unsigned short hzS [16 * 256];   //  8 KiB

    int wid = j >> 6, lane = j & 63;
    const float4* g4 = (const float4*)(gamma + lane * 12);
    const float4* e4 = (const float4*)(beta  + lane * 12);
    float4 G0 = g4[0], G1 = g4[1], G2 = g4[2];
    float4 E0 = e4[0], E1 = e4[1], E2 = e4[2];
    const unsigned short* xbase = xb  + row0 * D_MODEL;
    float*                obase = out + row0 * D_MODEL;

    auto LN_HALF = [&](int H) {
        #pragma unroll
        for (int r = wid; r < 16; r += 4) {
            uint4   hv = *(const uint4*)  &hxyS[r * 256 + 4 * lane];
            ushort4 zv = *(const ushort4*)&hzS [r * 256 + 4 * lane];
            float h[12];
            h[0]  = bf2f((unsigned short)(hv.x & 0xFFFF)); h[1]  = bf2f((unsigned short)(hv.x >> 16)); h[2]  = bf2f(zv.x);
            h[3]  = bf2f((unsigned short)(hv.y & 0xFFFF)); h[4]  = bf2f((unsigned short)(hv.y >> 16)); h[5]  = bf2f(zv.y);
            h[6]  = bf2f((unsigned short)(hv.z & 0xFFFF)); h[7]  = bf2f((unsigned short)(hv.z >> 16)); h[8]  = bf2f(zv.z);
            h[9]  = bf2f((unsigned short)(hv.w & 0xFFFF)); h[10] = bf2f((unsigned short)(hv.w >> 16)); h[11] = bf2f(zv.w);
            float sp = 0.f, qp = 0.f;
            #pragma unroll
            for (int k = 0; k < 12; ++k) { sp += h[k]; qp += h[k] * h[k]; }
            #pragma unroll
            for (int off = 1; off < 64; off <<= 1) {
                sp += __shfl_xor(sp, off);
                qp += __shfl_xor(qp, off);
            }
            float mean = sp * (1.f / 768.f);
            float var  = qp * (1.f / 768.f) - mean * mean;
            float rstd = rsqrtf(var + LN_EPS);

            int t = H * 16 + r;
            const unsigned short* xr2 = xbase + (size_t)t * D_MODEL + lane * 12;
            float*                or2 = obase + (size_t)t * D_MODEL + lane * 12;
            ushort4 Xa = *(const ushort4*)(xr2 + 0);
            ushort4 Xb = *(const ushort4*)(xr2 + 4);
            ushort4 Xc = *(const ushort4*)(xr2 + 8);
            float4 O0, O1, O2;
            O0.x = (h[0]  - mean) * rstd * G0.x + E0.x + bf2f(Xa.x);
            O0.y = (h[1]  - mean) * rstd * G0.y + E0.y + bf2f(Xa.y);
            O0.z = (h[2]  - mean) * rstd * G0.z + E0.z + bf2f(Xa.z);
            O0.w = (h[3]  - mean) * rstd * G0.w + E0.w + bf2f(Xa.w);
            O1.x = (h[4]  - mean) * rstd * G1.x + E1.x + bf2f(Xb.x);
            O1.y = (h[5]  - mean) * rstd * G1.y + E1.y + bf2f(Xb.y);
            O1.z = (h[6]  - mean) * rstd * G1.z + E1.z + bf2f(Xb.z);
            O1.w = (h[7]  - mean) * rstd * G1.w + E1.w + bf2f(Xb.w);
            O2.x = (h[8]  - mean) * rstd * G2.x + E2.x + bf2f(Xc.x);
            O2.y = (h[9]  - mean) * rstd * G2.y + E2.y + bf2f(Xc.y);
            O2.z = (h[10] - mean) * rstd * G2.z + E2.z + bf2f(Xc.z);
            O2.w = (h[11] - mean) * rstd * G2.w + E2.w + bf2f(Xc.w);
            *(float4*)(or2 + 0) = O0;
            *(float4*)(or2 + 4) = O1;
            *(float4*)(or2 + 8) = O2;
        }
    };

    u32x2 Ab0, Ab1, Ab2, Ai0, Ai1, Ai2; f32x4 Ad;
    u32x2 Bb0, Bb1, Bb2, Bi0, Bi1, Bi2; f32x4 Bd;

    #define LOADQH(P, q)                                                  \
        P##b0 = bv[(size_t)(q) * D_MODEL + 0];                            \
        P##b1 = bv[(size_t)(q) * D_MODEL + 1];                            \
        P##b2 = bv[(size_t)(q) * D_MODEL + 2];                            \
        P##i0 = ij[(size_t)(q) * D_MODEL + 0];                            \
        P##i1 = ij[(size_t)(q) * D_MODEL + 1];                            \
        P##i2 = ij[(size_t)(q) * D_MODEL + 2];                            \
        P##d  = *(const f32x4*)(dk + (q) * 4);

    // store at half-relative slot ((QBASE*4+k) & 15)
    #define PROC4H(P, QBASE)                                              \
        _Pragma("unroll")                                                 \
        for (int k = 0; k < 4; ++k) {                                     \
            float bx = bfx(P##b0, k), by = bfx(P##b1, k), bz = bfx(P##b2, k); \
            float ix = bfx(P##i0, k), iy = bfx(P##i1, k), iz = bfx(P##i2, k); \
            float d = P##d[k];                                            \
            QSTEP_H(bx, by, bz, ix, iy, iz, d)                            \
            int tt = (((QBASE) * 4 + k) & 15);                            \
            hxyS[tt * 256 + j] = (uint32_t)f2bf(hx) | ((uint32_t)f2bf(hy) << 16); \
            hzS [tt * 256 + j] = f2bf(hz);                                \
        }

    LOADQH(A, 0)
    LOADQH(B, 1)
    // half 0: quads 0..3 (steps 0..15); prefetch half-1 quads before the barrier
    PROC4H(A, 0) LOADQH(A, 2)
    PROC4H(B, 1) LOADQH(B, 3)
    PROC4H(A, 2) LOADQH(A, 4)
    PROC4H(B, 3) LOADQH(B, 5)
    __syncthreads();
    LN_HALF(0);                    // half-1 global loads in flight under the LN
    __syncthreads();
    // half 1: quads 4..7 (steps 16..31)
    PROC4H(A, 4) LOADQH(A, 6)
    PROC4H(B, 5) LOADQH(B, 7)
    PROC4H(A, 6)
    PROC4H(B, 7)
    __syncthreads();
    LN_HALF(1);

    #undef LOADQH
    #undef PROC4H
}

extern "C" void kernel_launch(void* const* d_in, const int* in_sizes, int n_in,
                              void* d_out, int out_size, void* d_ws, size_t ws_size,
                              hipStream_t stream) {
    const float* x     = (const float*)d_in[0];
    const float* W_biv = (const float*)d_in[1];
    const float* b_biv = (const float*)d_in[2];
    const float* W_dec = (const float*)d_in[3];
    const float* b_dec = (const float*)d_in[4];
    const float* W_in  = (const float*)d_in[5];
    const float* b_in  = (const float*)d_in[6];
    const float* gamma = (const float*)d_in[7];
    const float* beta  = (const float*)d_in[8];
    float* out = (float*)d_out;

    // workspace layout (153.5 MB); xb stays ALIVE through p3 (residual source)
    char* ws = (char*)d_ws;
    unsigned short* xb    = (unsigned short*)(ws);               // 50,331,648 B
    unsigned short* Wcat  = (unsigned short*)(ws + 50331648);    //  2,359,296 B (dead after GEMM)
    float*          decay = (float*)         (ws + 52690944);    //    131,072 B
    u32x2*          bivq  = (u32x2*)         (ws + 52822016);    // 50,331,648 B (quad-packed bf16)
    u32x2*          injq  = (u32x2*)         (ws + 103153664);   // 50,331,648 B (quad-packed bf16)
    // ops lives in d_out (used only between p1 and p2; p3 overwrites d_out later)
    float*          ops   = (float*)d_out;                       //  8,388,608 B
    // hs (bf16) reuses the dead Wcat region
    unsigned short* hsb   = (unsigned short*)(ws + 50331648);    //  1,572,864 B

    (void)in_sizes; (void)n_in; (void)out_size; (void)ws_size;

    // allow 128 KiB dynamic LDS for the GEMM (host-side attribute, graph-capture-safe)
    hipFuncSetAttribute((const void*)k_gemm_fused,
                        hipFuncAttributeMaxDynamicSharedMemorySize, 131072);

    k_conv      <<<M_ROWS + 1152, 256, 0, stream>>>(x, W_dec, b_dec, xb, decay, W_biv, W_in, Wcat);
    k_gemm_fused<<<GNBX * GNBY, 512, 131072, stream>>>(xb, Wcat, b_biv, b_in, bivq, injq);
    k_scan_p1   <<<1024, 256, 0, stream>>>(bivq, injq, decay, ops);
    k_scan_p2   <<<64,   64,  0, stream>>>(ops, hsb);
    k_scan_p3   <<<1024, 256, 0, stream>>>(bivq, injq, decay, hsb, xb, gamma, beta, out);
}